// Round 3
// baseline (710.567 us; speedup 1.0000x reference)
//
#include <hip/hip_runtime.h>
#include <math.h>

#define Bn 4
#define Cn 128
#define Hn 256
#define Wn 256
#define WFn 129
#define NBn 8
#define BLn 16
#define LAMv 0.01f
#define LSTR 260  // LDS row stride (floats): 16B-aligned rows, 4-bank row skew

// In-LDS 256-point radix-2 DIT FFT (SoA), cooperative across `nthr` threads
// (sub in [0,nthr)). Twiddle tables hold e^{-i*pi*k/128}; tsign=+1 forward,
// tsign=-1 inverse (conjugate twiddles). Unscaled. Starts and ends with a
// full-block barrier; all threads of the block must call it uniformly.
__device__ __forceinline__ void fft256_soa(float* re, float* im,
                                           const float* twc, const float* tws,
                                           int sub, int nthr, float tsign) {
  __syncthreads();
  for (int j = sub; j < 256; j += nthr) {
    int rj = (int)(__brev((unsigned)j) >> 24);
    if (rj > j) {
      float a = re[j]; re[j] = re[rj]; re[rj] = a;
      float b = im[j]; im[j] = im[rj]; im[rj] = b;
    }
  }
  __syncthreads();
  for (int len = 2; len <= 256; len <<= 1) {
    int half = len >> 1;
    int step = 256 / len;
    for (int j = sub; j < 128; j += nthr) {
      int pos = j & (half - 1);
      int i0 = ((j - pos) << 1) + pos;
      int i1 = i0 + half;
      float wc = twc[pos * step];
      float ws = tsign * tws[pos * step];
      float vr = re[i1], vi = im[i1];
      float tr = vr * wc - vi * ws;
      float ti = vr * ws + vi * wc;
      float ur = re[i0], ui = im[i0];
      re[i0] = ur + tr; im[i0] = ui + ti;
      re[i1] = ur - tr; im[i1] = ui - ti;
    }
    __syncthreads();
  }
}

__device__ __forceinline__ void init_tw(float* twc, float* tws, int t) {
  if (t < 128) {
    float s, c;
    sincospif((float)t / 128.0f, &s, &c);  // angle = pi*t/128
    twc[t] = c;
    tws[t] = -s;  // e^{-i*theta}
  }
}

// K1: real row-FFT along W for 16 rows per block; write spectrum TRANSPOSED
// [B*C][Wf][H] (float2) so the H-axis FFT in K2 reads contiguous columns.
// Forward ortho factor 1/256 applied at load.
__global__ __launch_bounds__(256, 4) void k_rowfft(const float* __restrict__ x,
                                                   float2* __restrict__ S) {
  int blk = blockIdx.x;
  int bc = blk >> 4;           // B*C plane, 0..511
  int h0 = (blk & 15) << 4;    // first of 16 rows
  __shared__ __align__(16) float ar[16][LSTR], ai[16][LSTR];
  __shared__ float twc[128], tws[128];
  int t = threadIdx.x;
  init_tw(twc, tws, t);
  const float4* xrow =
      (const float4*)(x + (size_t)bc * (Hn * Wn) + (size_t)h0 * Wn);
  const float sc = 1.0f / 256.0f;
  const float4 z4 = make_float4(0.f, 0.f, 0.f, 0.f);
#pragma unroll
  for (int j = 0; j < 4; j++) {
    int f4 = t + j * 256;        // 0..1023 float4s = 16 rows * 256 floats
    float4 v = xrow[f4];
    int r = f4 >> 6;
    int i = (f4 << 2) & 255;
    *(float4*)&ar[r][i] = make_float4(v.x * sc, v.y * sc, v.z * sc, v.w * sc);
    *(float4*)&ai[r][i] = z4;
  }
  int r = t >> 4, sub = t & 15;
  fft256_soa(&ar[r][0], &ai[r][0], twc, tws, sub, 16, 1.0f);
  // transposed store: for each wf, 16 consecutive h (128B) are contiguous
  for (int f = t; f < WFn * 16; f += 256) {
    int wf = f >> 4, rr = f & 15;
    S[((size_t)bc * WFn + wf) * Hn + (h0 + rr)] =
        make_float2(ar[rr][wf], ai[rr][wf]);
  }
}

// K2 (fused): per (b, block k, wf): forward FFT along H for the block's 16
// channels, complex block-MLP + softshrink gate at each h, inverse FFT along
// H. In-place on S. FFTs unscaled.
__global__ __launch_bounds__(256) void k_spectral(float2* __restrict__ S,
                                                  const float* __restrict__ w1,
                                                  const float* __restrict__ b1,
                                                  const float* __restrict__ w2,
                                                  const float* __restrict__ b2) {
  int blk = blockIdx.x;
  int wf = blk % WFn;
  int bk = blk / WFn;
  int k = bk & 7;
  int b = bk >> 3;
  __shared__ __align__(16) float ar[16][LSTR], ai[16][LSTR];
  __shared__ float twc[128], tws[128];
  __shared__ __align__(16) float w1r[256], w1i[256], w2r[256], w2i[256];
  __shared__ float b1r[16], b1i[16], b2r[16], b2i[16];
  int t = threadIdx.x;
  init_tw(twc, tws, t);
  // weights for this block k: w[part][k][i][o], i-major 16x16
  w1r[t] = w1[k * 256 + t];        w1i[t] = w1[(8 + k) * 256 + t];
  w2r[t] = w2[k * 256 + t];        w2i[t] = w2[(8 + k) * 256 + t];
  if (t < 16) {
    b1r[t] = b1[k * 16 + t];       b1i[t] = b1[(8 + k) * 16 + t];
    b2r[t] = b2[k * 16 + t];       b2i[t] = b2[(8 + k) * 16 + t];
  }
  int c = t >> 4, sub = t & 15;
  float2* col = S + ((size_t)(b * Cn + k * BLn + c) * WFn + wf) * Hn;
  const float4* col4 = (const float4*)col;
#pragma unroll
  for (int m = 0; m < 8; m++) {
    int hh = sub + m * 16;        // float4 index: holds h=2*hh, 2*hh+1
    float4 v = col4[hh];
    int h = hh << 1;
    ar[c][h] = v.x; ai[c][h] = v.y;
    ar[c][h + 1] = v.z; ai[c][h + 1] = v.w;
  }
  fft256_soa(&ar[c][0], &ai[c][0], twc, tws, sub, 16, 1.0f);

  // ---- block MLP + softshrink + spectral gate at h = t ----
  {
    const int h = t;
    const float4* W1R = (const float4*)w1r;
    const float4* W1I = (const float4*)w1i;
    const float4* W2R = (const float4*)w2r;
    const float4* W2I = (const float4*)w2i;
    float o1r[16], o1i[16];
#pragma unroll
    for (int o = 0; o < 16; o++) { o1r[o] = b1r[o]; o1i[o] = b1i[o]; }
#pragma unroll
    for (int i = 0; i < 16; i++) {
      float xri = ar[i][h];
      float xii = ai[i][h];
#pragma unroll
      for (int oq = 0; oq < 4; oq++) {
        float4 wr = W1R[i * 4 + oq];
        float4 wi = W1I[i * 4 + oq];
        o1r[oq * 4 + 0] = fmaf(xri, wr.x, fmaf(-xii, wi.x, o1r[oq * 4 + 0]));
        o1r[oq * 4 + 1] = fmaf(xri, wr.y, fmaf(-xii, wi.y, o1r[oq * 4 + 1]));
        o1r[oq * 4 + 2] = fmaf(xri, wr.z, fmaf(-xii, wi.z, o1r[oq * 4 + 2]));
        o1r[oq * 4 + 3] = fmaf(xri, wr.w, fmaf(-xii, wi.w, o1r[oq * 4 + 3]));
        o1i[oq * 4 + 0] = fmaf(xii, wr.x, fmaf(xri, wi.x, o1i[oq * 4 + 0]));
        o1i[oq * 4 + 1] = fmaf(xii, wr.y, fmaf(xri, wi.y, o1i[oq * 4 + 1]));
        o1i[oq * 4 + 2] = fmaf(xii, wr.z, fmaf(xri, wi.z, o1i[oq * 4 + 2]));
        o1i[oq * 4 + 3] = fmaf(xii, wr.w, fmaf(xri, wi.w, o1i[oq * 4 + 3]));
      }
    }
#pragma unroll
    for (int o = 0; o < 16; o++) {
      o1r[o] = fmaxf(o1r[o], 0.0f);
      o1i[o] = fmaxf(o1i[o], 0.0f);
    }
    float o2r[16], o2i[16];
#pragma unroll
    for (int o = 0; o < 16; o++) { o2r[o] = b2r[o]; o2i[o] = b2i[o]; }
#pragma unroll
    for (int i = 0; i < 16; i++) {
      float pr = o1r[i], pi = o1i[i];
#pragma unroll
      for (int oq = 0; oq < 4; oq++) {
        float4 wr = W2R[i * 4 + oq];
        float4 wi = W2I[i * 4 + oq];
        o2r[oq * 4 + 0] = fmaf(pr, wr.x, fmaf(-pi, wi.x, o2r[oq * 4 + 0]));
        o2r[oq * 4 + 1] = fmaf(pr, wr.y, fmaf(-pi, wi.y, o2r[oq * 4 + 1]));
        o2r[oq * 4 + 2] = fmaf(pr, wr.z, fmaf(-pi, wi.z, o2r[oq * 4 + 2]));
        o2r[oq * 4 + 3] = fmaf(pr, wr.w, fmaf(-pi, wi.w, o2r[oq * 4 + 3]));
        o2i[oq * 4 + 0] = fmaf(pi, wr.x, fmaf(pr, wi.x, o2i[oq * 4 + 0]));
        o2i[oq * 4 + 1] = fmaf(pi, wr.y, fmaf(pr, wi.y, o2i[oq * 4 + 1]));
        o2i[oq * 4 + 2] = fmaf(pi, wr.z, fmaf(pr, wi.z, o2i[oq * 4 + 2]));
        o2i[oq * 4 + 3] = fmaf(pi, wr.w, fmaf(pr, wi.w, o2i[oq * 4 + 3]));
      }
    }
#pragma unroll
    for (int o = 0; o < 16; o++) {
      float vr = o2r[o], vi = o2i[o];
      float sr = copysignf(fmaxf(fabsf(vr) - LAMv, 0.0f), vr);
      float si = copysignf(fmaxf(fabsf(vi) - LAMv, 0.0f), vi);
      float fr = ar[o][h], fi = ai[o][h];  // xf (2D spectrum) resident in LDS
      ar[o][h] = sr * fr - si * fi;
      ai[o][h] = sr * fi + si * fr;
    }
  }

  fft256_soa(&ar[c][0], &ai[c][0], twc, tws, sub, 16, -1.0f);
  float4* colw4 = (float4*)col;
#pragma unroll
  for (int m = 0; m < 8; m++) {
    int hh = sub + m * 16;
    int h = hh << 1;
    colw4[hh] = make_float4(ar[c][h], ai[c][h], ar[c][h + 1], ai[c][h + 1]);
  }
}

// K3: Hermitian reconstruction + inverse row FFT along W + ortho 1/256 +
// residual add, 16 rows per block.
__global__ __launch_bounds__(256, 4) void k_invrow(const float2* __restrict__ S,
                                                   const float* __restrict__ x,
                                                   float* __restrict__ out) {
  int blk = blockIdx.x;
  int bc = blk >> 4;
  int h0 = (blk & 15) << 4;
  __shared__ __align__(16) float ar[16][LSTR], ai[16][LSTR];
  __shared__ float twc[128], tws[128];
  int t = threadIdx.x;
  init_tw(twc, tws, t);
  for (int f = t; f < WFn * 16; f += 256) {
    int wf = f >> 4, rr = f & 15;
    float2 v = S[((size_t)bc * WFn + wf) * Hn + (h0 + rr)];
    ar[rr][wf] = v.x; ai[rr][wf] = v.y;
  }
  __syncthreads();
  // Hermitian fill: X[256-n] = conj(X[n]) for n=1..127
  for (int m = t; m < 127 * 16; m += 256) {
    int wf = 129 + (m >> 4), rr = m & 15;
    ar[rr][wf] = ar[rr][256 - wf];
    ai[rr][wf] = -ai[rr][256 - wf];
  }
  int r = t >> 4, sub = t & 15;
  fft256_soa(&ar[r][0], &ai[r][0], twc, tws, sub, 16, -1.0f);
  const float sc = 1.0f / 256.0f;  // inverse ortho factor for both axes
  size_t base = (size_t)bc * (Hn * Wn) + (size_t)h0 * Wn;
  const float4* x4 = (const float4*)(x + base);
  float4* o4 = (float4*)(out + base);
#pragma unroll
  for (int j = 0; j < 4; j++) {
    int f4 = t + j * 256;
    int rr = f4 >> 6, i = (f4 << 2) & 255;
    float4 v = *(const float4*)&ar[rr][i];
    float4 xv = x4[f4];
    o4[f4] = make_float4(fmaf(v.x, sc, xv.x), fmaf(v.y, sc, xv.y),
                         fmaf(v.z, sc, xv.z), fmaf(v.w, sc, xv.w));
  }
}

extern "C" void kernel_launch(void* const* d_in, const int* in_sizes, int n_in,
                              void* d_out, int out_size, void* d_ws,
                              size_t ws_size, hipStream_t stream) {
  const float* x  = (const float*)d_in[0];
  const float* w1 = (const float*)d_in[1];
  const float* b1 = (const float*)d_in[2];
  const float* w2 = (const float*)d_in[3];
  const float* b2 = (const float*)d_in[4];
  float* out = (float*)d_out;
  float2* S = (float2*)d_ws;  // [B*C][Wf][H] complex, ~135 MB

  k_rowfft<<<Bn * Cn * (Hn / 16), 256, 0, stream>>>(x, S);
  k_spectral<<<Bn * NBn * WFn, 256, 0, stream>>>(S, w1, b1, w2, b2);
  k_invrow<<<Bn * Cn * (Hn / 16), 256, 0, stream>>>(S, x, out);
}

// Round 4
// 444.315 us; speedup vs baseline: 1.5992x; 1.5992x over previous
//
#include <hip/hip_runtime.h>
#include <math.h>

#define Bn 4
#define Cn 128
#define Hn 256
#define Wn 256
#define WFn 129
#define NBn 8
#define BLn 16
#define LAMv 0.01f
#define LSTR 260  // LDS row stride (floats): 16B-aligned rows, 4-bank row skew

#define C1c 0.9238795325112867f  // cos(pi/8)
#define S1c 0.3826834323650898f  // sin(pi/8)
#define RTc 0.7071067811865476f  // sqrt(2)/2

__device__ constexpr int rev4(int j) {
  return ((j & 1) << 3) | ((j & 2) << 1) | ((j & 4) >> 1) | ((j & 8) >> 3);
}

// Fully-unrolled 16-point DIF FFT in registers. SIGN=+1: forward (e^{-i}),
// SIGN=-1: inverse (e^{+i}), unscaled. Natural input order; on return
// reg[j] holds X[rev4(j)].
template <int SIGN>
__device__ __forceinline__ void fft16(float* xr, float* xi) {
  const float g = (SIGN > 0) ? 1.0f : -1.0f;
  {  // stage len=16
    const float WC[8] = {1.f, C1c, RTc, S1c, 0.f, -S1c, -RTc, -C1c};
    const float WS[8] = {0.f, -S1c, -RTc, -C1c, -1.f, -C1c, -RTc, -S1c};
#pragma unroll
    for (int j = 0; j < 8; j++) {
      float ur = xr[j], ui = xi[j], vr = xr[j + 8], vi = xi[j + 8];
      float dr = ur - vr, di = ui - vi;
      xr[j] = ur + vr; xi[j] = ui + vi;
      float wc = WC[j], ws = g * WS[j];
      xr[j + 8] = dr * wc - di * ws;
      xi[j + 8] = dr * ws + di * wc;
    }
  }
  {  // stage len=8
    const float WC[4] = {1.f, RTc, 0.f, -RTc};
    const float WS[4] = {0.f, -RTc, -1.f, -RTc};
#pragma unroll
    for (int b = 0; b < 16; b += 8)
#pragma unroll
      for (int j = 0; j < 4; j++) {
        float ur = xr[b + j], ui = xi[b + j];
        float vr = xr[b + j + 4], vi = xi[b + j + 4];
        float dr = ur - vr, di = ui - vi;
        xr[b + j] = ur + vr; xi[b + j] = ui + vi;
        float wc = WC[j], ws = g * WS[j];
        xr[b + j + 4] = dr * wc - di * ws;
        xi[b + j + 4] = dr * ws + di * wc;
      }
  }
  {  // stage len=4: twiddles (1,0) and (0,-g)
#pragma unroll
    for (int b = 0; b < 16; b += 4) {
      {
        float ur = xr[b], ui = xi[b], vr = xr[b + 2], vi = xi[b + 2];
        xr[b] = ur + vr; xi[b] = ui + vi;
        xr[b + 2] = ur - vr; xi[b + 2] = ui - vi;
      }
      {
        float ur = xr[b + 1], ui = xi[b + 1], vr = xr[b + 3], vi = xi[b + 3];
        float dr = ur - vr, di = ui - vi;
        xr[b + 1] = ur + vr; xi[b + 1] = ui + vi;
        xr[b + 3] = g * di;   // (dr+i di)*(0,-g)
        xi[b + 3] = -g * dr;
      }
    }
  }
  {  // stage len=2
#pragma unroll
    for (int b = 0; b < 16; b += 2) {
      float ur = xr[b], ui = xi[b], vr = xr[b + 1], vi = xi[b + 1];
      xr[b] = ur + vr; xi[b] = ui + vi;
      xr[b + 1] = ur - vr; xi[b + 1] = ui - vi;
    }
  }
}

// Four-step 256-pt FFT: input regs v[m] = in[s + 16*m] (m=0..15) for thread
// s in [0,16). Uses re[]/im[] (>=256 floats) as transpose scratch (destroyed).
// On return reg[j] = OUT[16*rev4(j) + s]. Contains 3 block-wide barriers:
// ALL threads of the block must call uniformly. The first barrier orders any
// prior reads of re/im before the scratch writes; the last orders the scratch
// reads before any subsequent writes by the caller.
template <int SIGN>
__device__ __forceinline__ void fft256_4step(float* vr, float* vi,
                                             float* re, float* im, int s) {
  fft16<SIGN>(vr, vi);
  const float fs = (float)s;
#pragma unroll
  for (int j = 1; j < 16; j++) {  // j=0 -> k2=0 -> W^0=1
    const int k2 = rev4(j);
    float sn, cs;
    sincospif(fs * ((float)k2 / 128.0f), &sn, &cs);  // angle = pi*s*k2/128
    float ws = (SIGN > 0) ? -sn : sn;
    float r = vr[j] * cs - vi[j] * ws;
    vi[j] = vr[j] * ws + vi[j] * cs;
    vr[j] = r;
  }
  __syncthreads();
#pragma unroll
  for (int j = 0; j < 16; j++) {  // write G'[s][k2] at k2*16 + (s^k2)
    const int k2 = rev4(j);
    const int p = k2 * 16 + (s ^ k2);
    re[p] = vr[j]; im[p] = vi[j];
  }
  __syncthreads();
#pragma unroll
  for (int n1 = 0; n1 < 16; n1++) {  // read G'[n1][s] at s*16 + (n1^s)
    const int p = s * 16 + (n1 ^ s);
    vr[n1] = re[p]; vi[n1] = im[p];
  }
  __syncthreads();
  fft16<SIGN>(vr, vi);
}

// K1: real row-FFT along W, TWO ROWS PACKED per complex FFT (z = a + i*b),
// 32 rows per block. Unpack Xa/Xb from Z[k], conj(Z[256-k]) during the
// transposed store to S[B*C][Wf][H]. Forward ortho 1/256 applied at load.
__global__ __launch_bounds__(256) void k_rowfft(const float* __restrict__ x,
                                                float2* __restrict__ S) {
  int blk = blockIdx.x;
  int bc = blk >> 3;            // B*C plane, 0..511
  int h0 = (blk & 7) << 5;      // first of 32 rows
  __shared__ __align__(16) float zr[16][LSTR], zi[16][LSTR];
  int t = threadIdx.x;
  const float4* xrow =
      (const float4*)(x + (size_t)bc * (Hn * Wn) + (size_t)h0 * Wn);
  const float sc = 1.0f / 256.0f;
#pragma unroll
  for (int j = 0; j < 8; j++) {
    int f4 = t + j * 256;        // 0..2047 float4s = 32 rows * 256 floats
    float4 v = xrow[f4];
    int r = f4 >> 6;             // row 0..31
    int i = (f4 << 2) & 255;
    float* dst = (r & 1) ? &zi[r >> 1][i] : &zr[r >> 1][i];
    *(float4*)dst = make_float4(v.x * sc, v.y * sc, v.z * sc, v.w * sc);
  }
  __syncthreads();
  int p = t >> 4, s = t & 15;
  float vr[16], vi[16];
#pragma unroll
  for (int m = 0; m < 16; m++) {
    vr[m] = zr[p][s + 16 * m];
    vi[m] = zi[p][s + 16 * m];
  }
  fft256_4step<1>(vr, vi, &zr[p][0], &zi[p][0], s);
#pragma unroll
  for (int j = 0; j < 16; j++) {   // Z back to LDS in k-order
    int h = 16 * rev4(j) + s;
    zr[p][h] = vr[j]; zi[p][h] = vi[j];
  }
  __syncthreads();
  // unpack + transposed store: row 2p: A = (Z[k]+conj(Z[nk]))/2,
  // row 2p+1: B = (Z[k]-conj(Z[nk]))/(2i);   nk = (256-k) & 255
  for (int f = t; f < WFn * 32; f += 256) {
    int wf = f >> 5, rr = f & 31;
    int pp = rr >> 1;
    int nk = (256 - wf) & 255;
    float zkr = zr[pp][wf], zki = zi[pp][wf];
    float znr = zr[pp][nk], zni = zi[pp][nk];
    float re_, im_;
    if ((rr & 1) == 0) { re_ = 0.5f * (zkr + znr); im_ = 0.5f * (zki - zni); }
    else               { re_ = 0.5f * (zki + zni); im_ = 0.5f * (znr - zkr); }
    S[((size_t)bc * WFn + wf) * Hn + (h0 + rr)] = make_float2(re_, im_);
  }
}

// K2 (fused): per (b, block k, wcol): forward 256-pt FFT along H for 16
// channels (four-step in registers), complex block-MLP + softshrink gate at
// each h, inverse FFT along H. In-place on S. FFTs unscaled.
__global__ __launch_bounds__(256) void k_spectral(float2* __restrict__ S,
                                                  const float* __restrict__ w1,
                                                  const float* __restrict__ b1,
                                                  const float* __restrict__ w2,
                                                  const float* __restrict__ b2) {
  int blk = blockIdx.x;
  int wcol = blk % WFn;
  int bk = blk / WFn;
  int k = bk & 7;
  int b = bk >> 3;
  __shared__ __align__(16) float ar[16][LSTR], ai[16][LSTR];
  __shared__ __align__(16) float w1r[256], w1i[256], w2r[256], w2i[256];
  __shared__ float b1r[16], b1i[16], b2r[16], b2i[16];
  int t = threadIdx.x;
  // weights for this block k: w[part][k][i][o], i-major 16x16
  w1r[t] = w1[k * 256 + t];        w1i[t] = w1[(8 + k) * 256 + t];
  w2r[t] = w2[k * 256 + t];        w2i[t] = w2[(8 + k) * 256 + t];
  if (t < 16) {
    b1r[t] = b1[k * 16 + t];       b1i[t] = b1[(8 + k) * 16 + t];
    b2r[t] = b2[k * 16 + t];       b2i[t] = b2[(8 + k) * 16 + t];
  }
  int c = t >> 4, s = t & 15;
  float2* col = S + ((size_t)(b * Cn + k * BLn + c) * WFn + wcol) * Hn;
  float vr[16], vi[16];
#pragma unroll
  for (int m = 0; m < 16; m++) {   // strided load: 16 lanes x 8B contiguous
    float2 z = col[s + 16 * m];
    vr[m] = z.x; vi[m] = z.y;
  }
  fft256_4step<1>(vr, vi, &ar[c][0], &ai[c][0], s);
#pragma unroll
  for (int j = 0; j < 16; j++) {   // spectrum into LDS in h-order
    int h = 16 * rev4(j) + s;
    ar[c][h] = vr[j]; ai[c][h] = vi[j];
  }
  __syncthreads();  // also orders the weight-staging writes above

  // ---- block MLP + softshrink + spectral gate at h = t ----
  {
    const int h = t;
    const float4* W1R = (const float4*)w1r;
    const float4* W1I = (const float4*)w1i;
    const float4* W2R = (const float4*)w2r;
    const float4* W2I = (const float4*)w2i;
    float o1r[16], o1i[16];
#pragma unroll
    for (int o = 0; o < 16; o++) { o1r[o] = b1r[o]; o1i[o] = b1i[o]; }
#pragma unroll
    for (int i = 0; i < 16; i++) {
      float xri = ar[i][h];
      float xii = ai[i][h];
#pragma unroll
      for (int oq = 0; oq < 4; oq++) {
        float4 wr = W1R[i * 4 + oq];
        float4 wi = W1I[i * 4 + oq];
        o1r[oq * 4 + 0] = fmaf(xri, wr.x, fmaf(-xii, wi.x, o1r[oq * 4 + 0]));
        o1r[oq * 4 + 1] = fmaf(xri, wr.y, fmaf(-xii, wi.y, o1r[oq * 4 + 1]));
        o1r[oq * 4 + 2] = fmaf(xri, wr.z, fmaf(-xii, wi.z, o1r[oq * 4 + 2]));
        o1r[oq * 4 + 3] = fmaf(xri, wr.w, fmaf(-xii, wi.w, o1r[oq * 4 + 3]));
        o1i[oq * 4 + 0] = fmaf(xii, wr.x, fmaf(xri, wi.x, o1i[oq * 4 + 0]));
        o1i[oq * 4 + 1] = fmaf(xii, wr.y, fmaf(xri, wi.y, o1i[oq * 4 + 1]));
        o1i[oq * 4 + 2] = fmaf(xii, wr.z, fmaf(xri, wi.z, o1i[oq * 4 + 2]));
        o1i[oq * 4 + 3] = fmaf(xii, wr.w, fmaf(xri, wi.w, o1i[oq * 4 + 3]));
      }
    }
#pragma unroll
    for (int o = 0; o < 16; o++) {
      o1r[o] = fmaxf(o1r[o], 0.0f);
      o1i[o] = fmaxf(o1i[o], 0.0f);
    }
    float o2r[16], o2i[16];
#pragma unroll
    for (int o = 0; o < 16; o++) { o2r[o] = b2r[o]; o2i[o] = b2i[o]; }
#pragma unroll
    for (int i = 0; i < 16; i++) {
      float pr = o1r[i], pi = o1i[i];
#pragma unroll
      for (int oq = 0; oq < 4; oq++) {
        float4 wr = W2R[i * 4 + oq];
        float4 wi = W2I[i * 4 + oq];
        o2r[oq * 4 + 0] = fmaf(pr, wr.x, fmaf(-pi, wi.x, o2r[oq * 4 + 0]));
        o2r[oq * 4 + 1] = fmaf(pr, wr.y, fmaf(-pi, wi.y, o2r[oq * 4 + 1]));
        o2r[oq * 4 + 2] = fmaf(pr, wr.z, fmaf(-pi, wi.z, o2r[oq * 4 + 2]));
        o2r[oq * 4 + 3] = fmaf(pr, wr.w, fmaf(-pi, wi.w, o2r[oq * 4 + 3]));
        o2i[oq * 4 + 0] = fmaf(pi, wr.x, fmaf(pr, wi.x, o2i[oq * 4 + 0]));
        o2i[oq * 4 + 1] = fmaf(pi, wr.y, fmaf(pr, wi.y, o2i[oq * 4 + 1]));
        o2i[oq * 4 + 2] = fmaf(pi, wr.z, fmaf(pr, wi.z, o2i[oq * 4 + 2]));
        o2i[oq * 4 + 3] = fmaf(pi, wr.w, fmaf(pr, wi.w, o2i[oq * 4 + 3]));
      }
    }
#pragma unroll
    for (int o = 0; o < 16; o++) {
      float vr_ = o2r[o], vi_ = o2i[o];
      float sr = copysignf(fmaxf(fabsf(vr_) - LAMv, 0.0f), vr_);
      float si = copysignf(fmaxf(fabsf(vi_) - LAMv, 0.0f), vi_);
      float fr = ar[o][h], fi = ai[o][h];  // xf (2D spectrum) in LDS
      ar[o][h] = sr * fr - si * fi;
      ai[o][h] = sr * fi + si * fr;
    }
  }
  __syncthreads();
#pragma unroll
  for (int m = 0; m < 16; m++) {
    vr[m] = ar[c][s + 16 * m];
    vi[m] = ai[c][s + 16 * m];
  }
  fft256_4step<-1>(vr, vi, &ar[c][0], &ai[c][0], s);
#pragma unroll
  for (int j = 0; j < 16; j++) {
    int h = 16 * rev4(j) + s;
    col[h] = make_float2(vr[j], vi[j]);
  }
}

// K3: Hermitian reconstruction + inverse row FFT along W (four-step in regs)
// + ortho 1/256 + residual add, 16 rows per block.
__global__ __launch_bounds__(256) void k_invrow(const float2* __restrict__ S,
                                                const float* __restrict__ x,
                                                float* __restrict__ out) {
  int blk = blockIdx.x;
  int bc = blk >> 4;
  int h0 = (blk & 15) << 4;
  __shared__ __align__(16) float ar[16][LSTR], ai[16][LSTR];
  int t = threadIdx.x;
  for (int f = t; f < WFn * 16; f += 256) {
    int wf = f >> 4, rr = f & 15;
    float2 v = S[((size_t)bc * WFn + wf) * Hn + (h0 + rr)];
    ar[rr][wf] = v.x; ai[rr][wf] = v.y;
  }
  __syncthreads();
  // Hermitian fill: X[256-n] = conj(X[n]) for n=1..127
  for (int m = t; m < 127 * 16; m += 256) {
    int wf = 129 + (m >> 4), rr = m & 15;
    ar[rr][wf] = ar[rr][256 - wf];
    ai[rr][wf] = -ai[rr][256 - wf];
  }
  __syncthreads();
  int r = t >> 4, s = t & 15;
  float vr[16], vi[16];
#pragma unroll
  for (int m = 0; m < 16; m++) {
    vr[m] = ar[r][s + 16 * m];
    vi[m] = ai[r][s + 16 * m];
  }
  fft256_4step<-1>(vr, vi, &ar[r][0], &ai[r][0], s);
#pragma unroll
  for (int j = 0; j < 16; j++) {  // only the real part is needed
    ar[r][16 * rev4(j) + s] = vr[j];
  }
  __syncthreads();
  const float sc = 1.0f / 256.0f;  // inverse ortho factor for both axes
  size_t base = (size_t)bc * (Hn * Wn) + (size_t)h0 * Wn;
  const float4* x4 = (const float4*)(x + base);
  float4* o4 = (float4*)(out + base);
#pragma unroll
  for (int j = 0; j < 4; j++) {
    int f4 = t + j * 256;
    int rr = f4 >> 6, i = (f4 << 2) & 255;
    float4 v = *(const float4*)&ar[rr][i];
    float4 xv = x4[f4];
    o4[f4] = make_float4(fmaf(v.x, sc, xv.x), fmaf(v.y, sc, xv.y),
                         fmaf(v.z, sc, xv.z), fmaf(v.w, sc, xv.w));
  }
}

extern "C" void kernel_launch(void* const* d_in, const int* in_sizes, int n_in,
                              void* d_out, int out_size, void* d_ws,
                              size_t ws_size, hipStream_t stream) {
  const float* x  = (const float*)d_in[0];
  const float* w1 = (const float*)d_in[1];
  const float* b1 = (const float*)d_in[2];
  const float* w2 = (const float*)d_in[3];
  const float* b2 = (const float*)d_in[4];
  float* out = (float*)d_out;
  float2* S = (float2*)d_ws;  // [B*C][Wf][H] complex, ~135 MB

  k_rowfft<<<Bn * Cn * (Hn / 32), 256, 0, stream>>>(x, S);
  k_spectral<<<Bn * NBn * WFn, 256, 0, stream>>>(S, w1, b1, w2, b2);
  k_invrow<<<Bn * Cn * (Hn / 16), 256, 0, stream>>>(S, x, out);
}